// Round 3
// baseline (2278.465 us; speedup 1.0000x reference)
//
#include <hip/hip_runtime.h>

// ---------------------------------------------------------------------------
// SharedOnlyMLP: out = (silu(x@(gw*gs).T) * (x@(uw*us).T)) @ (dw*ds).T
// Round 3: 256x256-tile GEMM, 4-buffer LDS ring at BK=32 granularity:
//   - ring buf[s&3] (32 KiB each: A [256][32] + B [256][32], XOR-swizzled)
//   - step s: 2 phases {ds_read + stage(s+3) + barrier + setprio'd 16 MFMA}
//   - s_waitcnt vmcnt(8) once per step -> 12 loads in flight, issue->wait
//     distance ~5 phases (m201-depth pipeline)
//   - 8 waves (2Mx4N), per-wave 128x64 out, acc[8][4] of 16x16x32 MFMA
//   - bijective XCD swizzle; SiLU fused in up-GEMM epilogue
// ---------------------------------------------------------------------------

typedef __attribute__((ext_vector_type(8))) __bf16 bf16x8;
typedef __attribute__((ext_vector_type(4))) float f32x4;
typedef __attribute__((ext_vector_type(8))) unsigned short ushort8;

#define D_MODEL 4096
#define D_FF    11008
#define NTOK    8192

static __device__ __forceinline__ unsigned short f32_to_bf16(float f) {
    union { float f; unsigned u; } v; v.f = f;
    unsigned r = v.u + 0x7fffu + ((v.u >> 16) & 1u);   // round-nearest-even
    return (unsigned short)(r >> 16);
}
static __device__ __forceinline__ float bf16_to_f32(unsigned short s) {
    union { unsigned u; float f; } v; v.u = ((unsigned)s) << 16;
    return v.f;
}

static __device__ __forceinline__ void gload_lds16(const void* g, void* l) {
    __builtin_amdgcn_global_load_lds(
        (const __attribute__((address_space(1))) void*)g,
        (__attribute__((address_space(3))) void*)l, 16, 0, 0);
}

// ---- weight dequant: int32 (int8 values) * s[row] -> bf16, 8 elems/thread ----
__global__ __launch_bounds__(256)
void dequant_w_kernel(const int* __restrict__ w, const float* __restrict__ s,
                      unsigned short* __restrict__ out, int cols, long long total)
{
    long long i = ((long long)blockIdx.x * 256 + threadIdx.x) * 8;
    if (i >= total) return;
    float sc = s[(int)(i / cols)];
    int4 w0 = *(const int4*)(w + i);
    int4 w1 = *(const int4*)(w + i + 4);
    ushort8 r;
    r[0] = f32_to_bf16((float)w0.x * sc);
    r[1] = f32_to_bf16((float)w0.y * sc);
    r[2] = f32_to_bf16((float)w0.z * sc);
    r[3] = f32_to_bf16((float)w0.w * sc);
    r[4] = f32_to_bf16((float)w1.x * sc);
    r[5] = f32_to_bf16((float)w1.y * sc);
    r[6] = f32_to_bf16((float)w1.z * sc);
    r[7] = f32_to_bf16((float)w1.w * sc);
    *(ushort8*)(out + i) = r;
}

// ---- x: f32 -> bf16, 8 elems/thread ----
__global__ __launch_bounds__(256)
void cvt_x_kernel(const float* __restrict__ x, unsigned short* __restrict__ out,
                  long long total)
{
    long long i = ((long long)blockIdx.x * 256 + threadIdx.x) * 8;
    if (i >= total) return;
    float4 a = *(const float4*)(x + i);
    float4 b = *(const float4*)(x + i + 4);
    ushort8 r;
    r[0] = f32_to_bf16(a.x); r[1] = f32_to_bf16(a.y);
    r[2] = f32_to_bf16(a.z); r[3] = f32_to_bf16(a.w);
    r[4] = f32_to_bf16(b.x); r[5] = f32_to_bf16(b.y);
    r[6] = f32_to_bf16(b.z); r[7] = f32_to_bf16(b.w);
    *(ushort8*)(out + i) = r;
}

// ---------------------------------------------------------------------------
// 256^2 GEMM: C[M][N] = A[M][K] @ B[N][K]^T, 4-buffer BK=32 ring.
// Buffer b (32 KiB) at smem + b*32768: A [256][32] bf16 at +0, B at +16384.
// Row stride 64 B; swizzle: byte ^= (((row>>1)&3)<<4), applied both sides.
// ---------------------------------------------------------------------------
template<int MODE>
__global__ __launch_bounds__(512, 2)
void gemm256(const unsigned short* __restrict__ A,
             const unsigned short* __restrict__ B,
             void* __restrict__ C,
             const unsigned short* __restrict__ gateb,
             int M, int N, int K)
{
    extern __shared__ char smem[];
    const int tid = threadIdx.x;
    const int l   = tid & 63;
    const int w   = tid >> 6;
    const int wm  = w >> 2;          // 0..1
    const int wn  = w & 3;           // 0..3

    // bijective XCD swizzle (nwg % 8 == 0 for all our launches)
    const int nbx  = gridDim.x;
    const int nwg  = nbx * gridDim.y;
    const int orig = blockIdx.y * nbx + blockIdx.x;
    const int cpx  = nwg >> 3;
    const int swz  = (orig & 7) * cpx + (orig >> 3);
    const int bn = swz % nbx, bm = swz / nbx;
    const int m0 = bm * 256, n0 = bn * 256;

    // ---- staging lane geometry (pre-swizzled source column) ----
    const int st_r = w * 16 + (l >> 2);                    // row (instr 0)
    const int st_c = (((l & 3) ^ ((l >> 3) & 3)) << 3);    // elem col in 32-col step
    const unsigned short* gA = A + (size_t)(m0 + st_r) * K + st_c;
    const unsigned short* gB = B + (size_t)(n0 + st_r) * K + st_c;
    const size_t ld128 = (size_t)128 * K;

    // ---- ds_read lane offsets (swizzled) ----
    const int s4v = l >> 4;
    const int rA = wm * 128 + (l & 15);
    const int rB = wn * 64  + (l & 15);
    const int offA = rA * 64 + ((s4v << 4) ^ (((rA >> 1) & 3) << 4));
    const int offB = 16384 + rB * 64 + ((s4v << 4) ^ (((rB >> 1) & 3) << 4));

    f32x4 acc[8][4] = {};
    bf16x8 af[4], bfr[4];

#define SBAR()  __builtin_amdgcn_sched_barrier(0)
#define BAR()   __builtin_amdgcn_s_barrier()
#define VM8()   asm volatile("s_waitcnt vmcnt(8)" ::: "memory")

#define STAGE_A(SS, NXT) do { \
    const unsigned short* p_ = gA + ((size_t)(SS) << 5); \
    gload_lds16(p_,         smem + (NXT) + (w << 10)); \
    gload_lds16(p_ + ld128, smem + (NXT) + 8192 + (w << 10)); } while (0)
#define STAGE_B(SS, NXT) do { \
    const unsigned short* p_ = gB + ((size_t)(SS) << 5); \
    gload_lds16(p_,         smem + (NXT) + 16384 + (w << 10)); \
    gload_lds16(p_ + ld128, smem + (NXT) + 16384 + 8192 + (w << 10)); } while (0)

#define MFMA16(MB) do { \
    _Pragma("unroll") \
    for (int mi_ = 0; mi_ < 4; ++mi_) { \
        _Pragma("unroll") \
        for (int ni_ = 0; ni_ < 4; ++ni_) { \
            acc[(MB) + mi_][ni_] = __builtin_amdgcn_mfma_f32_16x16x32_bf16( \
                af[mi_], bfr[ni_], acc[(MB) + mi_][ni_], 0, 0, 0); \
        } } } while (0)

// One K-step (BK=32) = 2 phases. Reads buf CUR; stages step SS into buf NXT.
// vmcnt(8) once per step: 12 loads in flight max, waits for step s+1's 4.
#define STEP(CUR, NXT, SS) do { \
    /* phase 1: A mi0-3 + all B (8 ds_reads), stage A(SS) */ \
    af[0]  = *(const bf16x8*)(smem + (CUR) + offA); \
    af[1]  = *(const bf16x8*)(smem + (CUR) + offA + 1024); \
    af[2]  = *(const bf16x8*)(smem + (CUR) + offA + 2048); \
    af[3]  = *(const bf16x8*)(smem + (CUR) + offA + 3072); \
    bfr[0] = *(const bf16x8*)(smem + (CUR) + offB); \
    bfr[1] = *(const bf16x8*)(smem + (CUR) + offB + 1024); \
    bfr[2] = *(const bf16x8*)(smem + (CUR) + offB + 2048); \
    bfr[3] = *(const bf16x8*)(smem + (CUR) + offB + 3072); \
    STAGE_A(SS, NXT); \
    SBAR(); BAR(); \
    __builtin_amdgcn_s_setprio(1); MFMA16(0); __builtin_amdgcn_s_setprio(0); \
    SBAR(); BAR(); \
    /* phase 2: A mi4-7 (4 ds_reads), stage B(SS) */ \
    af[0] = *(const bf16x8*)(smem + (CUR) + offA + 4096); \
    af[1] = *(const bf16x8*)(smem + (CUR) + offA + 5120); \
    af[2] = *(const bf16x8*)(smem + (CUR) + offA + 6144); \
    af[3] = *(const bf16x8*)(smem + (CUR) + offA + 7168); \
    STAGE_B(SS, NXT); \
    SBAR(); BAR(); \
    __builtin_amdgcn_s_setprio(1); MFMA16(4); __builtin_amdgcn_s_setprio(0); \
    VM8(); SBAR(); BAR(); \
} while (0)

    // prologue: stage steps 0,1,2 into bufs 0,1,2 (12 loads); wait step 0
    STAGE_A(0, 0);      STAGE_B(0, 0);
    STAGE_A(1, 32768);  STAGE_B(1, 32768);
    STAGE_A(2, 65536);  STAGE_B(2, 65536);
    asm volatile("s_waitcnt vmcnt(8)" ::: "memory");
    SBAR(); BAR();

    const int T = K >> 5;            // 128 (K=4096) or 344 (K=11008); T%4==0
    #pragma unroll 1
    for (int s = 0; s < T; s += 4) {
        int s3 = s + 3; if (s3 >= T) s3 -= T;   // wrapped restage: harmless,
        int s4 = s + 4; if (s4 >= T) s4 -= T;   // keeps vmcnt counts uniform
        int s5 = s + 5; if (s5 >= T) s5 -= T;
        int s6 = s + 6; if (s6 >= T) s6 -= T;
        STEP(0,     98304, s3);
        STEP(32768, 0,     s4);
        STEP(65536, 32768, s5);
        STEP(98304, 65536, s6);
    }
    asm volatile("s_waitcnt vmcnt(0)" ::: "memory");    // drain dangling LDS writes

    // epilogue: C/D layout col=l&15, row=(l>>4)*4+q (m89-verified)
    const int er = (l >> 4) * 4;
    const int ec = l & 15;
    #pragma unroll
    for (int mi = 0; mi < 8; ++mi) {
        #pragma unroll
        for (int ni = 0; ni < 4; ++ni) {
            #pragma unroll
            for (int q = 0; q < 4; ++q) {
                int row = m0 + wm * 128 + mi * 16 + er + q;
                int col = n0 + wn * 64  + ni * 16 + ec;
                size_t idx = (size_t)row * N + col;
                float v = acc[mi][ni][q];
                if (MODE == 0) {
                    ((unsigned short*)C)[idx] = f32_to_bf16(v);
                } else if (MODE == 1) {
                    float g   = bf16_to_f32(gateb[idx]);
                    float sig = 1.0f / (1.0f + __expf(-g));
                    ((unsigned short*)C)[idx] = f32_to_bf16(g * sig * v);
                } else {
                    ((float*)C)[idx] = v;
                }
            }
        }
    }
#undef STEP
#undef MFMA16
#undef STAGE_A
#undef STAGE_B
#undef VM8
#undef BAR
#undef SBAR
}

extern "C" void kernel_launch(void* const* d_in, const int* in_sizes, int n_in,
                              void* d_out, int out_size, void* d_ws, size_t ws_size,
                              hipStream_t stream)
{
    const float* x  = (const float*)d_in[0];
    const int*   gw = (const int*)  d_in[1];
    const float* gs = (const float*)d_in[2];
    const int*   uw = (const int*)  d_in[3];
    const float* us = (const float*)d_in[4];
    const int*   dw = (const int*)  d_in[5];
    const float* dsc= (const float*)d_in[6];

    // workspace layout
    char* ws = (char*)d_ws;
    unsigned short* Xb = (unsigned short*)ws;  ws += (size_t)NTOK  * D_MODEL * 2;
    unsigned short* Wg = (unsigned short*)ws;  ws += (size_t)D_FF  * D_MODEL * 2;
    unsigned short* Wu = (unsigned short*)ws;  ws += (size_t)D_FF  * D_MODEL * 2;
    unsigned short* Wd = (unsigned short*)ws;  ws += (size_t)D_MODEL * D_FF * 2;
    unsigned short* H  = (unsigned short*)ws;  // NTOK * D_FF bf16 (gate, then h)

    const long long wtot = (long long)D_FF * D_MODEL;
    const long long xtot = (long long)NTOK * D_MODEL;

    // allow 128 KiB dynamic LDS (idempotent host-side calls; not stream ops)
    hipFuncSetAttribute(reinterpret_cast<const void*>(gemm256<0>),
                        hipFuncAttributeMaxDynamicSharedMemorySize, 131072);
    hipFuncSetAttribute(reinterpret_cast<const void*>(gemm256<1>),
                        hipFuncAttributeMaxDynamicSharedMemorySize, 131072);
    hipFuncSetAttribute(reinterpret_cast<const void*>(gemm256<2>),
                        hipFuncAttributeMaxDynamicSharedMemorySize, 131072);

    dequant_w_kernel<<<(int)(wtot / 2048), 256, 0, stream>>>(gw, gs,  Wg, D_MODEL, wtot);
    dequant_w_kernel<<<(int)(wtot / 2048), 256, 0, stream>>>(uw, us,  Wu, D_MODEL, wtot);
    dequant_w_kernel<<<(int)(wtot / 2048), 256, 0, stream>>>(dw, dsc, Wd, D_FF,    wtot);
    cvt_x_kernel    <<<(int)(xtot / 2048), 256, 0, stream>>>(x, Xb, xtot);

    dim3 blk(512);
    dim3 g1(D_FF / 256, NTOK / 256);     // 43 x 32 = 1376 blocks (%8==0)
    dim3 g3(D_MODEL / 256, NTOK / 256);  // 16 x 32 = 512 blocks (%8==0)

    // gate = Xb @ Wg^T -> H (bf16)
    gemm256<0><<<g1, blk, 131072, stream>>>(Xb, Wg, H, nullptr, NTOK, D_FF, D_MODEL);
    // up GEMM + fused h = silu(gate)*up -> H (in-place, same-index RMW)
    gemm256<1><<<g1, blk, 131072, stream>>>(Xb, Wu, H, H, NTOK, D_FF, D_MODEL);
    // out = H @ Wd^T -> f32 d_out
    gemm256<2><<<g3, blk, 131072, stream>>>(H, Wd, d_out, nullptr, NTOK, D_MODEL, D_FF);
}